// Round 16
// baseline (161.160 us; speedup 1.0000x reference)
//
#include <hip/hip_runtime.h>

#define BATCH 4
#define SEQ   1024
#define EMB   256
#define NH    12
#define EH    3072   // EMB*NH
#define MROWS 4096   // BATCH*SEQ

typedef __attribute__((ext_vector_type(8))) short bf16x8;
typedef __attribute__((ext_vector_type(4))) float f32x4;
typedef __attribute__((ext_vector_type(16))) float f32x16;
typedef __attribute__((ext_vector_type(4))) short short4v;

__device__ __forceinline__ short f2bf(float f) {
  union { float f; unsigned u; } x; x.f = f;
  unsigned r = x.u + 0x7fffu + ((x.u >> 16) & 1u);  // round-to-nearest-even
  return (short)(r >> 16);
}

// truncating bf16 pack for P (values in [0,1]; bias ~2^-10 rel, fine for P)
__device__ __forceinline__ unsigned pack_trunc(float a, float b) {
  union { float f; unsigned u; } x, y;
  x.f = a; y.f = b;
  return (x.u >> 16) | (y.u & 0xffff0000u);
}

__device__ __forceinline__ void gload_lds16(const void* g, void* l) {
  __builtin_amdgcn_global_load_lds(
      (const __attribute__((address_space(1))) unsigned*)g,
      (__attribute__((address_space(3))) unsigned*)l, 16, 0, 0);
}

// ---------------- cast x (fp32 -> bf16) ----------------
__global__ __launch_bounds__(256) void cast_x_kernel(const float* __restrict__ in,
                                                     short* __restrict__ out) {
  int i = (blockIdx.x * 256 + threadIdx.x) * 4;
  float4 v = *(const float4*)(in + i);
  short4v o;
  o[0] = f2bf(v.x); o[1] = f2bf(v.y); o[2] = f2bf(v.z); o[3] = f2bf(v.w);
  *(short4v*)(out + i) = o;
}

// ------- transpose + cast, fused QKV: z selects Wq/Wk/Wv (all [EMB][EH]) -------
__global__ __launch_bounds__(256) void transpose_qkv_kernel(const float* __restrict__ Wq,
                                                            const float* __restrict__ Wk,
                                                            const float* __restrict__ Wv,
                                                            short* __restrict__ Wt) {
  __shared__ float tile[32][33];
  const float* W = blockIdx.z == 0 ? Wq : (blockIdx.z == 1 ? Wk : Wv);
  short* o = Wt + (size_t)blockIdx.z * EH * EMB;
  const int n0 = blockIdx.x * 32, k0 = blockIdx.y * 32;
  const int tx = threadIdx.x & 31, ty = threadIdx.x >> 5;  // 32 x 8
#pragma unroll
  for (int i = 0; i < 4; i++)
    tile[ty + 8 * i][tx] = W[(size_t)(k0 + ty + 8 * i) * EH + n0 + tx];
  __syncthreads();
#pragma unroll
  for (int i = 0; i < 4; i++) {
    int nr = ty + 8 * i;
    o[(size_t)(n0 + nr) * EMB + k0 + tx] = f2bf(tile[tx][nr]);
  }
}

// ---------------- generic transpose + cast W[K][N] -> Wt[N][K] ----------------
__global__ __launch_bounds__(256) void transpose_cast_kernel(const float* __restrict__ W,
                                                             short* __restrict__ Wt,
                                                             int K, int N) {
  __shared__ float tile[32][33];
  const int n0 = blockIdx.x * 32, k0 = blockIdx.y * 32;
  const int tx = threadIdx.x & 31, ty = threadIdx.x >> 5;
#pragma unroll
  for (int i = 0; i < 4; i++)
    tile[ty + 8 * i][tx] = W[(size_t)(k0 + ty + 8 * i) * N + n0 + tx];
  __syncthreads();
#pragma unroll
  for (int i = 0; i < 4; i++) {
    int nr = ty + 8 * i;
    Wt[(size_t)(n0 + nr) * K + k0 + tx] = f2bf(tile[tx][nr]);
  }
}

// ------- fused QKV GEMM: BM=BN=128, BK=64 dbuf, swizzled. Regions 0/1 (q,k)
// use SWAPPED mfma operands -> packed short4 epilogue; region 2 (v) original.
__global__ __launch_bounds__(256) void qkv_gemm_kernel(const short* __restrict__ A,
                                                       const short* __restrict__ Bt,
                                                       const float* __restrict__ bq,
                                                       const float* __restrict__ bk,
                                                       const float* __restrict__ bv,
                                                       short* __restrict__ qout,
                                                       short* __restrict__ kout,
                                                       short* __restrict__ vout) {
  constexpr int BM = 128, BK = 64, K = EMB;
  __shared__ short As[2][BM * BK];
  __shared__ short Bs[2][BM * BK];
  const int tid = threadIdx.x;
  const int w = tid >> 6, lane = tid & 63;
  const int wm = w >> 1, wn = w & 1;
  const int l15 = lane & 15, l4 = lane >> 4;
  const int m0 = blockIdx.x * BM, n0 = blockIdx.y * BM;
  const int region = n0 / 3072;       // block-uniform
  const bool qk = (region < 2);

  f32x4 acc[4][4] = {};

  int srow[4], scol[4];
#pragma unroll
  for (int i = 0; i < 4; i++) {
    const int idx = i * 256 + tid;
    const int row = idx >> 3, sp = idx & 7, sl = sp ^ (row & 7);
    srow[i] = row;
    scol[i] = sl * 8;
  }

#define QKV_STAGE(bu, k0)                                                        \
  {                                                                              \
    _Pragma("unroll") for (int i = 0; i < 4; i++) {                              \
      const int idx = i * 256 + tid;                                             \
      gload_lds16(A + (size_t)(m0 + srow[i]) * K + (k0) + scol[i],               \
                  (char*)&As[bu][0] + idx * 16);                                 \
      gload_lds16(Bt + (size_t)(n0 + srow[i]) * K + (k0) + scol[i],              \
                  (char*)&Bs[bu][0] + idx * 16);                                 \
    }                                                                            \
  }

  QKV_STAGE(0, 0);
  asm volatile("s_waitcnt vmcnt(0)" ::: "memory");
  __syncthreads();

  int bu = 0;
  for (int k0 = 0; k0 < K; k0 += BK) {
    if (k0 + BK < K) QKV_STAGE(bu ^ 1, k0 + BK);

#pragma unroll
    for (int kst = 0; kst < 2; kst++) {
      const int sp = (kst * 4 + l4) ^ (l15 & 7);
      bf16x8 af[4], bfr[4];
#pragma unroll
      for (int mt = 0; mt < 4; mt++)
        af[mt] = *(const bf16x8*)&As[bu][(wm * 64 + mt * 16 + l15) * 64 + sp * 8];
#pragma unroll
      for (int nt = 0; nt < 4; nt++)
        bfr[nt] = *(const bf16x8*)&Bs[bu][(wn * 64 + nt * 16 + l15) * 64 + sp * 8];
      __builtin_amdgcn_s_setprio(1);
      if (qk) {
#pragma unroll
        for (int mt = 0; mt < 4; mt++)
#pragma unroll
          for (int nt = 0; nt < 4; nt++)
            acc[mt][nt] = __builtin_amdgcn_mfma_f32_16x16x32_bf16(bfr[nt], af[mt], acc[mt][nt], 0, 0, 0);
      } else {
#pragma unroll
        for (int mt = 0; mt < 4; mt++)
#pragma unroll
          for (int nt = 0; nt < 4; nt++)
            acc[mt][nt] = __builtin_amdgcn_mfma_f32_16x16x32_bf16(af[mt], bfr[nt], acc[mt][nt], 0, 0, 0);
      }
      __builtin_amdgcn_s_setprio(0);
    }

    asm volatile("s_waitcnt vmcnt(0)" ::: "memory");
    __syncthreads();
    bu ^= 1;
  }

  const float kQScale = 0.09016844f;  // (1/16) * log2(e)
  if (qk) {
    short* C = region == 0 ? qout : kout;
    const float* bias = region == 0 ? bq : bk;
    const float sc = region == 0 ? kQScale : 1.0f;
#pragma unroll
    for (int nt = 0; nt < 4; nt++) {
      const int coln0 = (n0 - region * 3072) + wn * 64 + nt * 16 + 4 * l4;
      const float4 bv4 = *(const float4*)&bias[coln0];
#pragma unroll
      for (int mt = 0; mt < 4; mt++) {
        const int m = m0 + wm * 64 + mt * 16 + l15;
        f32x4 v = acc[mt][nt];
        short4v o4;
        o4[0] = f2bf((v[0] + bv4.x) * sc);
        o4[1] = f2bf((v[1] + bv4.y) * sc);
        o4[2] = f2bf((v[2] + bv4.z) * sc);
        o4[3] = f2bf((v[3] + bv4.w) * sc);
        *(short4v*)&C[(size_t)m * EH + coln0] = o4;
      }
    }
  } else {
#pragma unroll
    for (int nt = 0; nt < 4; nt++) {
      const int n = n0 + wn * 64 + nt * 16 + l15;
      const int col = n - 2 * 3072;
      const float bvv = bv[col];
#pragma unroll
      for (int mt = 0; mt < 4; mt++) {
        const int mrow = m0 + wm * 64 + mt * 16 + 4 * l4;
        f32x4 v = acc[mt][nt];
        const int bb = mrow >> 10;
        const int s  = mrow & 1023;
        const int h  = col >> 8, d = col & 255;
        short4v o4;
        o4[0] = f2bf(v[0] + bvv); o4[1] = f2bf(v[1] + bvv);
        o4[2] = f2bf(v[2] + bvv); o4[3] = f2bf(v[3] + bvv);
        *(short4v*)&vout[((size_t)(bb * NH + h) * EMB + d) * SEQ + s] = o4;
      }
    }
  }
#undef QKV_STAGE
}

// ------- fc partial GEMM (split-K x4) -------
__global__ __launch_bounds__(256) void fc_partial_kernel(const short* __restrict__ A,
                                                         const short* __restrict__ Bt,
                                                         float* __restrict__ Pout,
                                                         int M, int N, int K) {
  constexpr int BM = 64, BK = 128, KSL = 768;
  __shared__ short As[2][BM * BK];
  __shared__ short Bs[2][BM * BK];
  const int tid = threadIdx.x;
  const int w = tid >> 6, lane = tid & 63;
  const int wm = w >> 1, wn = w & 1;
  const int l15 = lane & 15, l4 = lane >> 4;
  const int m0 = blockIdx.x * BM, n0 = blockIdx.y * BM;
  const int kbase = blockIdx.z * KSL;
  float* P = Pout + (size_t)blockIdx.z * M * N;

  f32x4 acc[2][2] = {};

  int srow[4], scol[4];
#pragma unroll
  for (int i = 0; i < 4; i++) {
    const int idx = i * 256 + tid;
    const int row = idx >> 4, sp = idx & 15, sl = sp ^ (row & 15);
    srow[i] = row;
    scol[i] = sl * 8;
  }

#define FC_STAGE(bu, k0)                                                         \
  {                                                                              \
    _Pragma("unroll") for (int i = 0; i < 4; i++) {                              \
      const int idx = i * 256 + tid;                                             \
      gload_lds16(A + (size_t)(m0 + srow[i]) * K + (k0) + scol[i],               \
                  (char*)&As[bu][0] + idx * 16);                                 \
      gload_lds16(Bt + (size_t)(n0 + srow[i]) * K + (k0) + scol[i],              \
                  (char*)&Bs[bu][0] + idx * 16);                                 \
    }                                                                            \
  }

  FC_STAGE(0, kbase);
  asm volatile("s_waitcnt vmcnt(0)" ::: "memory");
  __syncthreads();

  int bu = 0;
  for (int k0 = kbase; k0 < kbase + KSL; k0 += BK) {
    if (k0 + BK < kbase + KSL) FC_STAGE(bu ^ 1, k0 + BK);

#pragma unroll
    for (int kst = 0; kst < 4; kst++) {
      const int sp = (kst * 4 + l4) ^ l15;
      bf16x8 af[2], bfr[2];
#pragma unroll
      for (int mt = 0; mt < 2; mt++)
        af[mt] = *(const bf16x8*)&As[bu][(wm * 32 + mt * 16 + l15) * 128 + sp * 8];
#pragma unroll
      for (int nt = 0; nt < 2; nt++)
        bfr[nt] = *(const bf16x8*)&Bs[bu][(wn * 32 + nt * 16 + l15) * 128 + sp * 8];
      __builtin_amdgcn_s_setprio(1);
#pragma unroll
      for (int mt = 0; mt < 2; mt++)
#pragma unroll
        for (int nt = 0; nt < 2; nt++)
          acc[mt][nt] = __builtin_amdgcn_mfma_f32_16x16x32_bf16(af[mt], bfr[nt], acc[mt][nt], 0, 0, 0);
      __builtin_amdgcn_s_setprio(0);
    }

    asm volatile("s_waitcnt vmcnt(0)" ::: "memory");
    __syncthreads();
    bu ^= 1;
  }

#pragma unroll
  for (int nt = 0; nt < 2; nt++) {
    const int n = n0 + wn * 32 + nt * 16 + l15;
#pragma unroll
    for (int mt = 0; mt < 2; mt++) {
      const int mrow = m0 + wm * 32 + mt * 16 + 4 * l4;
      f32x4 v = acc[mt][nt];
#pragma unroll
      for (int r = 0; r < 4; r++)
        P[(size_t)(mrow + r) * N + n] = v[r];
    }
  }
#undef FC_STAGE
}

// ------- fc reduce -------
__global__ __launch_bounds__(256) void fc_reduce_kernel(const float* __restrict__ Pin,
                                                        const float* __restrict__ bias,
                                                        float* __restrict__ out) {
  const int i4 = (blockIdx.x * 256 + threadIdx.x) * 4;
  const int n = i4 & 255;
  float4 s = *(const float4*)(bias + n);
#pragma unroll
  for (int ks = 0; ks < 4; ks++) {
    float4 p = *(const float4*)(Pin + (size_t)ks * MROWS * EMB + i4);
    s.x += p.x; s.y += p.y; s.z += p.z; s.w += p.w;
  }
  *(float4*)(out + i4) = s;
}

// ---------------- causal flash attention (32x32 MFMA, 32 q/wave) -------------
// grid (48, 8) heavy-first (qt = 7-by). 4 waves x 32 q = QBLK 128, KVBLK=32,
// dbuf K+V, LDS 64KB -> 2 blocks/CU (8 waves, 2/SIMD). 32x32x16 MFMA doubles
// FLOP per ds_read_b128: 128 reads per block-tile vs 264 in the 16x16 form.
// Swapped ops keep q on lane&31 for S AND O: softmax reduce = 1 shfl_xor(32);
// fsc/inv are per-lane scalars (no broadcasts). P B-fragment built in-register
// (pack_trunc + 2 shfl_xor per 16-kv step) -> no Ps LDS. All pk[] indices are
// compile-time (rule #20: ternary selects for the l5-dependent choice).
__global__ __launch_bounds__(256) void attn_kernel(const short* __restrict__ Q,
                                                   const short* __restrict__ Kg,
                                                   const short* __restrict__ Vt,
                                                   short* __restrict__ Ctx) {
  __shared__ short Ks[2][8192];   // [buf][32 kv][32 seg16B], seg low3 ^= kv&7
  __shared__ short Vs[2][8192];   // [buf][128 dp][8 seg16B], seg ^= dp&7 (R8 layout)
  const int tid = threadIdx.x, w = tid >> 6, lane = tid & 63;
  const int l31 = lane & 31, l5 = lane >> 5, l1 = lane & 1;
  const int bh = blockIdx.x, b = bh / NH, h = bh % NH;
  const int qt = (gridDim.y - 1) - blockIdx.y;   // heavy-first
  const int q0 = qt * 128;
  const int qw0 = q0 + w * 32;                   // wave owns 32 q-rows
  const int qglob = qw0 + l31;                   // this lane's q column
  const int ntiles = 4 * qt + 4;                 // 32-kv tiles

  const float kMaskL2 = -14426.95f;   // -10000 * log2(e)
  const float kThrL2  = 11.5f;        // ~8 nats defer threshold

  const short* Kbase = Kg + (size_t)b * SEQ * EH + h * EMB;
  const short* Vbase = Vt + (size_t)bh * EMB * SEQ;

  // stage source offsets: 4 K + 4 V chunks per thread (1024 idx x 16B each)
  int koff[4], voff[4];
#pragma unroll
  for (int i = 0; i < 4; i++) {
    const int idx = i * 256 + tid;     // [0, 1024)
    {
      const int kv = idx >> 5, sp = idx & 31;
      const int sl = (sp & 24) | ((sp & 7) ^ (kv & 7));
      koff[i] = kv * EH + sl * 8;
    }
    {
      const int dp = idx >> 3, sp = idx & 7, sl = sp ^ (dp & 7);
      voff[i] = (dp * 2 + (sl >> 2)) * SEQ + (sl & 3) * 8;
    }
  }

  // Q fragments (B-operand): col q = l31, k-rows d = i*16 + 8*l5 + e
  bf16x8 qf[16];
  {
    const short* qp = Q + (size_t)(b * SEQ + qglob) * EH + h * EMB + 8 * l5;
#pragma unroll
    for (int i = 0; i < 16; i++) qf[i] = *(const bf16x8*)(qp + 16 * i);
  }

  // prologue: stage tile 0 -> buf 0
#pragma unroll
  for (int i = 0; i < 4; i++) {
    const int idx = i * 256 + tid;
    gload_lds16(Kbase + koff[i], (char*)&Ks[0][0] + idx * 16);
    gload_lds16(Vbase + voff[i], (char*)&Vs[0][0] + idx * 16);
  }
  asm volatile("s_waitcnt vmcnt(0)" ::: "memory");
  __syncthreads();

  f32x16 o[8] = {};                  // O^T[256 d][32 q], 8 x 32x32 tiles
  float mst = -1e30f, lst = 0.f;     // per-lane (q = qglob); pair-partial l

  int bu = 0;
  for (int t = 0; t < ntiles; t++) {
    const int kv0 = t * 32;

    // ---- issue next-tile stage into buf^1 (hides under compute) ----
    if (t + 1 < ntiles) {
      const short* kp = Kbase + (size_t)(kv0 + 32) * EH;
      const short* vp = Vbase + kv0 + 32;
#pragma unroll
      for (int i = 0; i < 4; i++) {
        const int idx = i * 256 + tid;
        gload_lds16(kp + koff[i], (char*)&Ks[bu ^ 1][0] + idx * 16);
        gload_lds16(vp + voff[i], (char*)&Vs[bu ^ 1][0] + idx * 16);
      }
    }

    if (kv0 <= qw0 + 31) {   // wave-uniform: skip fully-masked tiles
      // ---- S^T[32 kv][32 q] = K Q^T via 16 x mfma_32x32x16 ----
      f32x16 s = {};
      __builtin_amdgcn_s_setprio(1);
#pragma unroll
      for (int dstep = 0; dstep < 16; dstep++) {
        const int seg = dstep * 2 + l5;
        const int phys = (seg & 24) | ((seg & 7) ^ (l31 & 7));
        bf16x8 kf = *(const bf16x8*)&Ks[bu][l31 * 256 + phys * 8];
        s = __builtin_amdgcn_mfma_f32_32x32x16_bf16(kf, qf[dstep], s, 0, 0, 0);
      }
      __builtin_amdgcn_s_setprio(0);

      // ---- softmax: rows kv = kv0 + (reg&3) + 8*(reg>>2) + 4*l5, col q ----
      const bool maskt = (kv0 + 31 > qw0);
      float sval[16];
      float mxl = -1e30f;
#pragma unroll
      for (int g = 0; g < 4; g++)
#pragma unroll
        for (int r = 0; r < 4; r++) {
          float v = s[4 * g + r];
          if (maskt) {
            const int kv = kv0 + 8 * g + 4 * l5 + r;
            v += (kv > qglob) ? kMaskL2 : 0.0f;
          }
          sval[4 * g + r] = v;
          mxl = fmaxf(mxl, v);
        }
      float mx = fmaxf(mxl, __shfl_xor(mxl, 32));
      const bool skipt = __all(mx <= mst + kThrL2);
      float mref, fsc;
      if (skipt) {
        fsc = 1.0f;
        mref = mst;
      } else {
        float mnew = fmaxf(mst, mx);
        fsc = exp2f(mst - mnew);
        mst = mnew;
        mref = mnew;
      }
      float pp[16];
      float lsum = 0.f;
#pragma unroll
      for (int j = 0; j < 16; j++) {
        float e = exp2f(sval[j] - mref);
        pp[j] = e;
        lsum += e;
      }
      lst = lst * fsc + lsum;   // partial over this lane-pair half

      if (!skipt) {
#pragma unroll
        for (int dt = 0; dt < 8; dt++)
#pragma unroll
          for (int j = 0; j < 16; j++) o[dt][j] *= fsc;   // q is per-lane: scalar fsc
      }

      // ---- pack P to bf16 pairs: pk[g] covers kv = 8g + 4*l5 + {0..3} ----
      unsigned pk0a = pack_trunc(pp[0], pp[1]),   pk0b = pack_trunc(pp[2], pp[3]);
      unsigned pk1a = pack_trunc(pp[4], pp[5]),   pk1b = pack_trunc(pp[6], pp[7]);
      unsigned pk2a = pack_trunc(pp[8], pp[9]),   pk2b = pack_trunc(pp[10], pp[11]);
      unsigned pk3a = pack_trunc(pp[12], pp[13]), pk3b = pack_trunc(pp[14], pp[15]);

      // ---- O += P V over 2 ks-steps of 16 kv ----
      __builtin_amdgcn_s_setprio(1);
#pragma unroll
      for (int ks = 0; ks < 2; ks++) {
        // B-fragment rows: kv = ks*16 + 8*l5 + e, col q = l31
        const unsigned ownA = ks ? pk2a : pk0a, ownB = ks ? pk2b : pk0b;
        const unsigned othA = ks ? pk3a : pk1a, othB = ks ? pk3b : pk1b;
        const unsigned sendA = l5 ? ownA : othA;   // pk[2ks + (l5^1)]
        const unsigned sendB = l5 ? ownB : othB;
        const unsigned recvA = (unsigned)__shfl_xor((int)sendA, 32);
        const unsigned recvB = (unsigned)__shfl_xor((int)sendB, 32);
        union { unsigned u[4]; bf16x8 v; } bb;
        bb.u[0] = l5 ? recvA : ownA;
        bb.u[1] = l5 ? recvB : ownB;
        bb.u[2] = l5 ? othA : recvA;
        bb.u[3] = l5 ? othB : recvB;
        const bf16x8 bfrag = bb.v;
#pragma unroll
        for (int dt = 0; dt < 8; dt++) {
          const int dp = dt * 16 + (l31 >> 1);
          const int sl = l1 * 4 + 2 * ks + l5;
          const int phys = sl ^ (dp & 7);
          bf16x8 vf = *(const bf16x8*)&Vs[bu][dp * 64 + phys * 8];
          o[dt] = __builtin_amdgcn_mfma_f32_32x32x16_bf16(vf, bfrag, o[dt], 0, 0, 0);
        }
      }
      __builtin_amdgcn_s_setprio(0);
    }

    // ---- single per-tile sync: next stage complete + all reads done ----
    asm volatile("s_waitcnt vmcnt(0)" ::: "memory");
    __syncthreads();
    bu ^= 1;
  }

  // ---- finish: l reduce across lane pair, per-lane normalize, store ----
  lst += __shfl_xor(lst, 32);
  const float inv = 1.f / lst;
  short* cp = Ctx + (size_t)(b * SEQ + qglob) * EH + h * EMB;
#pragma unroll
  for (int dt = 0; dt < 8; dt++)
#pragma unroll
    for (int g = 0; g < 4; g++) {
      const int d = 32 * dt + 8 * g + 4 * l5;
      short4v o4;
      o4[0] = f2bf(o[dt][4 * g + 0] * inv);
      o4[1] = f2bf(o[dt][4 * g + 1] * inv);
      o4[2] = f2bf(o[dt][4 * g + 2] * inv);
      o4[3] = f2bf(o[dt][4 * g + 3] * inv);
      *(short4v*)&cp[d] = o4;
    }
}

extern "C" void kernel_launch(void* const* d_in, const int* in_sizes, int n_in,
                              void* d_out, int out_size, void* d_ws, size_t ws_size,
                              hipStream_t stream) {
  const float* x   = (const float*)d_in[0];
  const float* Wq  = (const float*)d_in[2];
  const float* bq  = (const float*)d_in[3];
  const float* Wk  = (const float*)d_in[4];
  const float* bk  = (const float*)d_in[5];
  const float* Wv  = (const float*)d_in[6];
  const float* bv  = (const float*)d_in[7];
  const float* Wfc = (const float*)d_in[8];
  const float* bfc = (const float*)d_in[9];
  float* out = (float*)d_out;

  short* ws    = (short*)d_ws;
  short* xb    = ws;                  // 4096*256
  short* wqkvt = xb + 1048576;        // 3*3072*256 contiguous [9216][256]
  short* wfct  = wqkvt + 3 * 786432;  // 256*3072
  short* q     = wfct + 786432;       // 4096*3072 (pre-scaled by log2e/16)
  short* k     = q + 12582912;
  short* vt    = k + 12582912;        // [b][h][d][s]
  short* ctx   = vt + 12582912;       // 4096*3072
  float* fcp   = (float*)q;           // fc f32 partials alias q (dead after attn)

  cast_x_kernel<<<1024, 256, 0, stream>>>(x, xb);
  transpose_qkv_kernel<<<dim3(EH / 32, EMB / 32, 3), 256, 0, stream>>>(Wq, Wk, Wv, wqkvt);
  transpose_cast_kernel<<<dim3(EMB / 32, EH / 32), 256, 0, stream>>>(Wfc, wfct, EH, EMB);

  qkv_gemm_kernel<<<dim3(MROWS / 128, 9216 / 128), 256, 0, stream>>>(
      xb, wqkvt, bq, bk, bv, q, k, vt);

  attn_kernel<<<dim3(BATCH * NH, SEQ / 128), 256, 0, stream>>>(q, k, vt, ctx);

  fc_partial_kernel<<<dim3(MROWS / 64, EMB / 64, 4), 256, 0, stream>>>(
      ctx, wfct, fcp, MROWS, EMB, EH);
  fc_reduce_kernel<<<(MROWS * EMB / 4) / 256, 256, 0, stream>>>(fcp, bfc, out);
}